// Round 1
// baseline (397.709 us; speedup 1.0000x reference)
//
#include <hip/hip_runtime.h>
#include <hip/hip_bf16.h>
#include <cstdint>
#include <math.h>

#define DEVINL __device__ __forceinline__

typedef __attribute__((ext_vector_type(8))) __bf16 bf16x8;
typedef __attribute__((ext_vector_type(4))) float floatx4;

constexpr int TB = 2;        // batch
constexpr int TT = 2048;     // seq len
constexpr int TC = 2048;     // channels
constexpr int NH = 16, NKV = 4, HD = 128;
constexpr int MR = TB * TT;           // 4096 token rows
constexpr int NQ = NH * HD;           // 2048
constexpr int NK = NKV * HD;          // 512
constexpr int NQKV = NQ + 2 * NK;     // 3072

// ---------- helpers ----------
DEVINL unsigned bfbits(float f) {  // fp32 -> bf16 bits, RNE
  unsigned u = __builtin_bit_cast(unsigned, f);
  return (u + 0x7FFFu + ((u >> 16) & 1u)) >> 16;
}
DEVINL int pack2bf(float lo, float hi) {
  return (int)(bfbits(lo) | (bfbits(hi) << 16));
}
DEVINL void gl_lds16(const __hip_bfloat16* g, __hip_bfloat16* l) {
  // 16B per lane, LDS dest = wave-uniform base + lane*16
  __builtin_amdgcn_global_load_lds(
      (const __attribute__((address_space(1))) unsigned int*)g,
      (__attribute__((address_space(3))) unsigned int*)l, 16, 0, 0);
}
DEVINL floatx4 mfma16(bf16x8 a, bf16x8 b, floatx4 c) {
  return __builtin_amdgcn_mfma_f32_16x16x32_bf16(a, b, c, 0, 0, 0);
}
DEVINL void cstore(float* p, float v) { *p = v; }
DEVINL void cstore(__hip_bfloat16* p, float v) { *(unsigned short*)p = (unsigned short)bfbits(v); }

// ---------- fp32 -> bf16 convert ----------
__global__ __launch_bounds__(256) void k_cvt(const float* __restrict__ s,
                                             __hip_bfloat16* __restrict__ d, int n) {
  int i = (blockIdx.x * 256 + threadIdx.x) * 4;
  if (i >= n) return;
  float4 v = *(const float4*)(s + i);
  ushort4 o;
  o.x = (unsigned short)bfbits(v.x);
  o.y = (unsigned short)bfbits(v.y);
  o.z = (unsigned short)bfbits(v.z);
  o.w = (unsigned short)bfbits(v.w);
  *(ushort4*)(d + i) = o;
}

// ---------- GEMM: C[M,N] = A[M,K] @ B[N,K]^T  (m97 structure) ----------
template <typename OUT_T>
__global__ __launch_bounds__(256, 2) void k_gemm_bt(
    const __hip_bfloat16* __restrict__ A, const __hip_bfloat16* __restrict__ B,
    OUT_T* __restrict__ C, int M, int N, int K) {
  __shared__ __align__(16) __hip_bfloat16 As[128 * 32];
  __shared__ __align__(16) __hip_bfloat16 Bs[128 * 32];
  const int tid = threadIdx.x;
  const int lane = tid & 63, w = tid >> 6;
  const int q15 = lane & 15, quad = lane >> 4;
  const int wm = w >> 1, wn = w & 1;
  const int tm = blockIdx.y, tn = blockIdx.x;

  const int r0 = tid >> 2, c0 = (tid & 3) * 8;   // staging: 4 lanes cover one 64B row-chunk
  const __hip_bfloat16* a0 = A + (size_t)(tm * 128 + r0) * K + c0;
  const __hip_bfloat16* a1 = A + (size_t)(tm * 128 + r0 + 64) * K + c0;
  const __hip_bfloat16* b0 = B + (size_t)(tn * 128 + r0) * K + c0;
  const __hip_bfloat16* b1 = B + (size_t)(tn * 128 + r0 + 64) * K + c0;
  __hip_bfloat16* lA0 = As + (tid & ~63) * 8;
  __hip_bfloat16* lA1 = As + 2048 + (tid & ~63) * 8;
  __hip_bfloat16* lB0 = Bs + (tid & ~63) * 8;
  __hip_bfloat16* lB1 = Bs + 2048 + (tid & ~63) * 8;

  floatx4 acc[4][4] = {};
  for (int k0 = 0; k0 < K; k0 += 32) {
    __syncthreads();
    gl_lds16(a0 + k0, lA0);
    gl_lds16(a1 + k0, lA1);
    gl_lds16(b0 + k0, lB0);
    gl_lds16(b1 + k0, lB1);
    __syncthreads();
    bf16x8 af[4], bfr[4];
#pragma unroll
    for (int i = 0; i < 4; i++)
      af[i] = *(const bf16x8*)(As + (wm * 64 + i * 16 + q15) * 32 + quad * 8);
#pragma unroll
    for (int i = 0; i < 4; i++)
      bfr[i] = *(const bf16x8*)(Bs + (wn * 64 + i * 16 + q15) * 32 + quad * 8);
#pragma unroll
    for (int mi = 0; mi < 4; mi++)
#pragma unroll
      for (int ni = 0; ni < 4; ni++)
        acc[mi][ni] = mfma16(af[mi], bfr[ni], acc[mi][ni]);
  }
#pragma unroll
  for (int mi = 0; mi < 4; mi++) {
    int row0 = tm * 128 + wm * 64 + mi * 16 + quad * 4;
#pragma unroll
    for (int ni = 0; ni < 4; ni++) {
      int col = tn * 128 + wn * 64 + ni * 16 + q15;
#pragma unroll
      for (int r = 0; r < 4; r++)
        cstore(C + (size_t)(row0 + r) * N + col, acc[mi][ni][r]);
    }
  }
}

// ---------- fused RMSNorm + RoPE + layout for q,k ----------
// one wave per (b,t,head); lane holds elems (lane, lane+64) == RoPE pair.
// q additionally scaled by log2(e)/sqrt(HD) so attention can use exp2.
__global__ __launch_bounds__(256) void k_ropenorm(
    const __hip_bfloat16* __restrict__ qkv,
    __hip_bfloat16* __restrict__ q_l, __hip_bfloat16* __restrict__ k_l) {
  int gw = (blockIdx.x * 256 + threadIdx.x) >> 6;
  int lane = threadIdx.x & 63;
  int head = gw % 20;
  int bt = gw / 20;
  int b = bt >> 11, t = bt & (TT - 1);
  bool isq = head < NH;
  int h = isq ? head : head - NH;
  const __hip_bfloat16* src = qkv + (size_t)bt * NQKV + (isq ? h * HD : NQ + h * HD);
  float x1 = __bfloat162float(src[lane]);
  float x2 = __bfloat162float(src[lane + 64]);
  float ss = x1 * x1 + x2 * x2;
#pragma unroll
  for (int m = 1; m < 64; m <<= 1) ss += __shfl_xor(ss, m, 64);
  float rinv = rsqrtf(ss * (1.0f / 128.0f) + 1.1920928955078125e-07f);
  // inv_freq = 10000^(-lane/64) = 2^(-lane*log2(10000)/64)
  float ang = (float)t * exp2f((float)lane * -(13.287712379549449f / 64.0f));
  float sv = sinf(ang), cv = cosf(ang);
  float scale = isq ? (1.4426950408889634f * 0.08838834764831845f) : 1.0f;
  float o1 = (x1 * cv + x2 * sv) * rinv * scale;
  float o2 = (x2 * cv - x1 * sv) * rinv * scale;
  __hip_bfloat16* dst = isq ? q_l + ((size_t)(b * NH + h) * TT + t) * HD
                            : k_l + ((size_t)(b * NKV + h) * TT + t) * HD;
  *(unsigned short*)(dst + lane) = (unsigned short)bfbits(o1);
  *(unsigned short*)(dst + lane + 64) = (unsigned short)bfbits(o2);
}

// ---------- V transpose: qkv v-cols -> vt[b][hk][d][t] ----------
__global__ __launch_bounds__(256) void k_vtrans(const __hip_bfloat16* __restrict__ qkv,
                                                __hip_bfloat16* __restrict__ vt) {
  __shared__ __hip_bfloat16 tile[64][130];  // 130: conflict-free transpose stride
  int bid = blockIdx.x;
  int t0 = (bid & 31) * 64;
  int hk = (bid >> 5) & 3;
  int b = bid >> 7;
  int tid = threadIdx.x;
#pragma unroll
  for (int j = 0; j < 32; j++) {
    int e = j * 256 + tid;
    int tt = e >> 7, d = e & 127;
    tile[tt][d] = qkv[(size_t)(b * TT + t0 + tt) * NQKV + NQ + NK + hk * HD + d];
  }
  __syncthreads();
#pragma unroll
  for (int j = 0; j < 32; j++) {
    int e = j * 256 + tid;
    int d = e >> 6, tt = e & 63;
    vt[(((size_t)(b * NKV + hk)) * HD + d) * TT + t0 + tt] = tile[tt][d];
  }
}

// ---------- flash attention (causal, GQA) ----------
// Computes S^T = K@Q^T so softmax rows live in lane&15; P^T -> B-operand via shuffles;
// PV as y^T = V^T @ P^T with V pre-transposed. XOR chunk swizzle breaks LDS bank aliasing.
__global__ __launch_bounds__(256, 2) void k_attn(
    const __hip_bfloat16* __restrict__ q_l, const __hip_bfloat16* __restrict__ k_l,
    const __hip_bfloat16* __restrict__ vt_l, __hip_bfloat16* __restrict__ y) {
  __shared__ __align__(16) __hip_bfloat16 Qs[64 * 128];
  __shared__ __align__(16) __hip_bfloat16 Ks[64 * 128];
  __shared__ __align__(16) __hip_bfloat16 Vs[128 * 64];
  const int tid = threadIdx.x, lane = tid & 63, w = tid >> 6;
  const int q15 = lane & 15, quad = lane >> 4;
  const int qb = gridDim.x - 1 - blockIdx.x;  // longest blocks first
  const int h = blockIdx.y, b = blockIdx.z;
  const int hk = h >> 2;

  const __hip_bfloat16* qbase = q_l + ((size_t)(b * NH + h) * TT + qb * 64) * HD;
  const __hip_bfloat16* kbase = k_l + (size_t)(b * NKV + hk) * TT * HD;
  const __hip_bfloat16* vbase = vt_l + (size_t)(b * NKV + hk) * HD * TT;

  // stage Q once (swizzled): slot s -> row s>>4, lds chunk s&15 holds global chunk (s&15)^(row&15)
#pragma unroll
  for (int i = 0; i < 4; i++) {
    int s = i * 256 + tid;
    int r = s >> 4, c = s & 15;
    gl_lds16(qbase + r * HD + (c ^ (r & 15)) * 8, Qs + (i * 256 + (tid & ~63)) * 8);
  }

  floatx4 ot[8] = {};
  float m_run = -INFINITY, l_run = 0.0f;
  const int s0lane = ((quad & 1) << 1) * 16 + q15;
  const int s1lane = s0lane + 16;
  const bool hi = quad >= 2;

  for (int kb = 0; kb <= qb; kb++) {
    __syncthreads();
#pragma unroll
    for (int i = 0; i < 4; i++) {
      int s = i * 256 + tid;
      {
        int r = s >> 4, c = s & 15;
        gl_lds16(kbase + (size_t)(kb * 64 + r) * HD + (c ^ (r & 15)) * 8,
                 Ks + (i * 256 + (tid & ~63)) * 8);
      }
      {
        int r = s >> 3, c = s & 7;
        gl_lds16(vbase + (size_t)r * TT + kb * 64 + (c ^ (r & 7)) * 8,
                 Vs + (i * 256 + (tid & ~63)) * 8);
      }
    }
    __syncthreads();

    bf16x8 qf[4];
#pragma unroll
    for (int dc = 0; dc < 4; dc++) {
      int r = w * 16 + q15, c = dc * 4 + quad;
      qf[dc] = *(const bf16x8*)(Qs + (r * 16 + (c ^ (r & 15))) * 8);
    }
    floatx4 st[4] = {};
#pragma unroll
    for (int kt = 0; kt < 4; kt++) {
      int r = kt * 16 + q15;
#pragma unroll
      for (int dc = 0; dc < 4; dc++) {
        int c = dc * 4 + quad;
        bf16x8 kf = *(const bf16x8*)(Ks + (r * 16 + (c ^ (r & 15))) * 8);
        st[kt] = mfma16(kf, qf[dc], st[kt]);  // S^T[key][q]
      }
    }
    if (kb == qb) {  // causal mask, diagonal block only
      int qg = w * 16 + q15;
#pragma unroll
      for (int kt = 0; kt < 4; kt++)
#pragma unroll
        for (int r = 0; r < 4; r++)
          if (kt * 16 + quad * 4 + r > qg) st[kt][r] = -INFINITY;
    }
    // online softmax; q-row == lane&15, keys spread over regs (in-lane) + quads
    float mloc = -INFINITY;
#pragma unroll
    for (int kt = 0; kt < 4; kt++)
#pragma unroll
      for (int r = 0; r < 4; r++) mloc = fmaxf(mloc, st[kt][r]);
    mloc = fmaxf(mloc, __shfl_xor(mloc, 16, 64));
    mloc = fmaxf(mloc, __shfl_xor(mloc, 32, 64));
    float m_new = fmaxf(m_run, mloc);
    float alpha = exp2f(m_run - m_new);  // first block: exp2(-inf)=0
    float rsum = 0.f;
    int pk[4][2];
#pragma unroll
    for (int kt = 0; kt < 4; kt++) {
      float p0 = exp2f(st[kt][0] - m_new);
      float p1 = exp2f(st[kt][1] - m_new);
      float p2 = exp2f(st[kt][2] - m_new);
      float p3 = exp2f(st[kt][3] - m_new);
      rsum += (p0 + p1) + (p2 + p3);
      pk[kt][0] = pack2bf(p0, p1);
      pk[kt][1] = pack2bf(p2, p3);
    }
    rsum += __shfl_xor(rsum, 16, 64);
    rsum += __shfl_xor(rsum, 32, 64);
    l_run = l_run * alpha + rsum;
    m_run = m_new;
#pragma unroll
    for (int dt = 0; dt < 8; dt++) {
      ot[dt][0] *= alpha; ot[dt][1] *= alpha;
      ot[dt][2] *= alpha; ot[dt][3] *= alpha;
    }
    // P^T C-layout -> B-operand frags via shuffles, then PV
#pragma unroll
    for (int kc = 0; kc < 2; kc++) {
      int lo0 = __shfl(pk[kc * 2][0], s0lane, 64);
      int lo1 = __shfl(pk[kc * 2][1], s0lane, 64);
      int lo2 = __shfl(pk[kc * 2][0], s1lane, 64);
      int lo3 = __shfl(pk[kc * 2][1], s1lane, 64);
      int h0 = __shfl(pk[kc * 2 + 1][0], s0lane, 64);
      int h1 = __shfl(pk[kc * 2 + 1][1], s0lane, 64);
      int h2 = __shfl(pk[kc * 2 + 1][0], s1lane, 64);
      int h3 = __shfl(pk[kc * 2 + 1][1], s1lane, 64);
      union { int i[4]; bf16x8 v; } pu;
      pu.i[0] = hi ? h0 : lo0;
      pu.i[1] = hi ? h1 : lo1;
      pu.i[2] = hi ? h2 : lo2;
      pu.i[3] = hi ? h3 : lo3;
      bf16x8 pf = pu.v;
#pragma unroll
      for (int dt = 0; dt < 8; dt++) {
        int r = dt * 16 + q15, c = kc * 4 + quad;
        bf16x8 vf = *(const bf16x8*)(Vs + (r * 8 + (c ^ (r & 7))) * 8);
        ot[dt] = mfma16(vf, pf, ot[dt]);  // y^T[d][q]
      }
    }
  }
  // epilogue: y[b][t][h*128+d]
  float linv = 1.0f / l_run;
  int t = qb * 64 + w * 16 + q15;
  __hip_bfloat16* yrow = y + (size_t)(b * TT + t) * TC + h * HD;
#pragma unroll
  for (int dt = 0; dt < 8; dt++) {
    int d = dt * 16 + quad * 4;
    ushort4 o;
    o.x = (unsigned short)bfbits(ot[dt][0] * linv);
    o.y = (unsigned short)bfbits(ot[dt][1] * linv);
    o.z = (unsigned short)bfbits(ot[dt][2] * linv);
    o.w = (unsigned short)bfbits(ot[dt][3] * linv);
    *(ushort4*)(yrow + d) = o;
  }
}

// ---------- launcher ----------
extern "C" void kernel_launch(void* const* d_in, const int* in_sizes, int n_in,
                              void* d_out, int out_size, void* d_ws, size_t ws_size,
                              hipStream_t stream) {
  (void)in_sizes; (void)n_in; (void)out_size; (void)ws_size;
  const float* x  = (const float*)d_in[0];
  const float* Wq = (const float*)d_in[1];
  const float* Wk = (const float*)d_in[2];
  const float* Wv = (const float*)d_in[3];
  const float* Wo = (const float*)d_in[4];
  float* out = (float*)d_out;

  char* ws = (char*)d_ws;
  size_t off = 0;
  auto alloc = [&](size_t bytes) {
    void* p = ws + off;
    off += (bytes + 255) & ~(size_t)255;
    return p;
  };
  __hip_bfloat16* xb   = (__hip_bfloat16*)alloc((size_t)MR * TC * 2);
  __hip_bfloat16* wqkv = (__hip_bfloat16*)alloc((size_t)NQKV * TC * 2);
  __hip_bfloat16* wo   = (__hip_bfloat16*)alloc((size_t)TC * TC * 2);
  __hip_bfloat16* qkv  = (__hip_bfloat16*)alloc((size_t)MR * NQKV * 2);
  __hip_bfloat16* q_l  = (__hip_bfloat16*)alloc((size_t)TB * NH * TT * HD * 2);
  __hip_bfloat16* k_l  = (__hip_bfloat16*)alloc((size_t)TB * NKV * TT * HD * 2);
  __hip_bfloat16* vt_l = (__hip_bfloat16*)alloc((size_t)TB * NKV * HD * TT * 2);
  __hip_bfloat16* yb   = (__hip_bfloat16*)alloc((size_t)MR * TC * 2);

  auto cvt = [&](const float* s, __hip_bfloat16* d, int n) {
    k_cvt<<<(n / 4 + 255) / 256, 256, 0, stream>>>(s, d, n);
  };
  cvt(x, xb, MR * TC);
  cvt(Wq, wqkv, NQ * TC);
  cvt(Wk, wqkv + (size_t)NQ * TC, NK * TC);
  cvt(Wv, wqkv + (size_t)(NQ + NK) * TC, NK * TC);
  cvt(Wo, wo, TC * TC);

  // fused QKV projection: [4096,3072] = xb @ wqkv^T
  k_gemm_bt<__hip_bfloat16><<<dim3(NQKV / 128, MR / 128), 256, 0, stream>>>(
      xb, wqkv, qkv, MR, NQKV, TC);

  // RMSNorm + RoPE + layout (one wave per (b,t,head)): 4096*20 waves / 4 per block
  k_ropenorm<<<(MR * 20) / 4, 256, 0, stream>>>(qkv, q_l, k_l);
  k_vtrans<<<TB * NKV * (TT / 64), 256, 0, stream>>>(qkv, vt_l);

  // flash attention
  k_attn<<<dim3(TT / 64, NH, TB), 256, 0, stream>>>(q_l, k_l, vt_l, yb);

  // output projection (fp32 out)
  k_gemm_bt<float><<<dim3(TC / 128, MR / 128), 256, 0, stream>>>(
      yb, wo, out, MR, TC, TC);
}

// Round 2
// 330.893 us; speedup vs baseline: 1.2019x; 1.2019x over previous
//
#include <hip/hip_runtime.h>
#include <hip/hip_bf16.h>
#include <cstdint>
#include <math.h>

#define DEVINL __device__ __forceinline__

typedef __attribute__((ext_vector_type(8))) __bf16 bf16x8;
typedef __attribute__((ext_vector_type(4))) float floatx4;

constexpr int TB = 2;        // batch
constexpr int TT = 2048;     // seq len
constexpr int TC = 2048;     // channels
constexpr int NH = 16, NKV = 4, HD = 128;
constexpr int MR = TB * TT;           // 4096 token rows
constexpr int NQ = NH * HD;           // 2048
constexpr int NK = NKV * HD;          // 512
constexpr int NQKV = NQ + 2 * NK;     // 3072

// ---------- helpers ----------
DEVINL unsigned bfbits(float f) {  // fp32 -> bf16 bits, RNE
  unsigned u = __builtin_bit_cast(unsigned, f);
  return (u + 0x7FFFu + ((u >> 16) & 1u)) >> 16;
}
DEVINL int pack2bf(float lo, float hi) {
  return (int)(bfbits(lo) | (bfbits(hi) << 16));
}
DEVINL void gl_lds16(const __hip_bfloat16* g, __hip_bfloat16* l) {
  // 16B per lane, LDS dest = wave-uniform base + lane*16
  __builtin_amdgcn_global_load_lds(
      (const __attribute__((address_space(1))) unsigned int*)g,
      (__attribute__((address_space(3))) unsigned int*)l, 16, 0, 0);
}
DEVINL floatx4 mfma16(bf16x8 a, bf16x8 b, floatx4 c) {
  return __builtin_amdgcn_mfma_f32_16x16x32_bf16(a, b, c, 0, 0, 0);
}
DEVINL void cstore(float* p, float v) { *p = v; }
DEVINL void cstore(__hip_bfloat16* p, float v) { *(unsigned short*)p = (unsigned short)bfbits(v); }

// ---------- fused fp32 -> bf16 convert (all 5 inputs, one launch) ----------
__global__ __launch_bounds__(256) void k_cvt5(
    const float* __restrict__ s0, const float* __restrict__ s1,
    const float* __restrict__ s2, const float* __restrict__ s3,
    const float* __restrict__ s4,
    __hip_bfloat16* __restrict__ d0, __hip_bfloat16* __restrict__ d1,
    __hip_bfloat16* __restrict__ d2, __hip_bfloat16* __restrict__ d3,
    __hip_bfloat16* __restrict__ d4) {
  const float* s;
  __hip_bfloat16* d;
  int n;
  switch (blockIdx.y) {
    case 0: s = s0; d = d0; n = MR * TC; break;
    case 1: s = s1; d = d1; n = NQ * TC; break;
    case 2: s = s2; d = d2; n = NK * TC; break;
    case 3: s = s3; d = d3; n = NK * TC; break;
    default: s = s4; d = d4; n = TC * TC; break;
  }
  int i = (blockIdx.x * 256 + threadIdx.x) * 4;
  if (i >= n) return;
  float4 v = *(const float4*)(s + i);
  ushort4 o;
  o.x = (unsigned short)bfbits(v.x);
  o.y = (unsigned short)bfbits(v.y);
  o.z = (unsigned short)bfbits(v.z);
  o.w = (unsigned short)bfbits(v.w);
  *(ushort4*)(d + i) = o;
}

// ---------- GEMM: C[M,N] = A[M,K] @ B[N,K]^T  (m97 structure) ----------
template <typename OUT_T>
__global__ __launch_bounds__(256, 2) void k_gemm_bt(
    const __hip_bfloat16* __restrict__ A, const __hip_bfloat16* __restrict__ B,
    OUT_T* __restrict__ C, int M, int N, int K) {
  __shared__ __align__(16) __hip_bfloat16 As[128 * 32];
  __shared__ __align__(16) __hip_bfloat16 Bs[128 * 32];
  const int tid = threadIdx.x;
  const int lane = tid & 63, w = tid >> 6;
  const int q15 = lane & 15, quad = lane >> 4;
  const int wm = w >> 1, wn = w & 1;
  const int tm = blockIdx.y, tn = blockIdx.x;

  const int r0 = tid >> 2, c0 = (tid & 3) * 8;   // staging: 4 lanes cover one 64B row-chunk
  const __hip_bfloat16* a0 = A + (size_t)(tm * 128 + r0) * K + c0;
  const __hip_bfloat16* a1 = A + (size_t)(tm * 128 + r0 + 64) * K + c0;
  const __hip_bfloat16* b0 = B + (size_t)(tn * 128 + r0) * K + c0;
  const __hip_bfloat16* b1 = B + (size_t)(tn * 128 + r0 + 64) * K + c0;
  __hip_bfloat16* lA0 = As + (tid & ~63) * 8;
  __hip_bfloat16* lA1 = As + 2048 + (tid & ~63) * 8;
  __hip_bfloat16* lB0 = Bs + (tid & ~63) * 8;
  __hip_bfloat16* lB1 = Bs + 2048 + (tid & ~63) * 8;

  floatx4 acc[4][4] = {};
  for (int k0 = 0; k0 < K; k0 += 32) {
    __syncthreads();
    gl_lds16(a0 + k0, lA0);
    gl_lds16(a1 + k0, lA1);
    gl_lds16(b0 + k0, lB0);
    gl_lds16(b1 + k0, lB1);
    __syncthreads();
    bf16x8 af[4], bfr[4];
#pragma unroll
    for (int i = 0; i < 4; i++)
      af[i] = *(const bf16x8*)(As + (wm * 64 + i * 16 + q15) * 32 + quad * 8);
#pragma unroll
    for (int i = 0; i < 4; i++)
      bfr[i] = *(const bf16x8*)(Bs + (wn * 64 + i * 16 + q15) * 32 + quad * 8);
#pragma unroll
    for (int mi = 0; mi < 4; mi++)
#pragma unroll
      for (int ni = 0; ni < 4; ni++)
        acc[mi][ni] = mfma16(af[mi], bfr[ni], acc[mi][ni]);
  }
#pragma unroll
  for (int mi = 0; mi < 4; mi++) {
    int row0 = tm * 128 + wm * 64 + mi * 16 + quad * 4;
#pragma unroll
    for (int ni = 0; ni < 4; ni++) {
      int col = tn * 128 + wn * 64 + ni * 16 + q15;
#pragma unroll
      for (int r = 0; r < 4; r++)
        cstore(C + (size_t)(row0 + r) * N + col, acc[mi][ni][r]);
    }
  }
}

// ---------- fused RMSNorm + RoPE + layout for q,k ----------
__global__ __launch_bounds__(256) void k_ropenorm(
    const __hip_bfloat16* __restrict__ qkv,
    __hip_bfloat16* __restrict__ q_l, __hip_bfloat16* __restrict__ k_l) {
  int gw = (blockIdx.x * 256 + threadIdx.x) >> 6;
  int lane = threadIdx.x & 63;
  int head = gw % 20;
  int bt = gw / 20;
  int b = bt >> 11, t = bt & (TT - 1);
  bool isq = head < NH;
  int h = isq ? head : head - NH;
  const __hip_bfloat16* src = qkv + (size_t)bt * NQKV + (isq ? h * HD : NQ + h * HD);
  float x1 = __bfloat162float(src[lane]);
  float x2 = __bfloat162float(src[lane + 64]);
  float ss = x1 * x1 + x2 * x2;
#pragma unroll
  for (int m = 1; m < 64; m <<= 1) ss += __shfl_xor(ss, m, 64);
  float rinv = rsqrtf(ss * (1.0f / 128.0f) + 1.1920928955078125e-07f);
  float ang = (float)t * exp2f((float)lane * -(13.287712379549449f / 64.0f));
  float sv = sinf(ang), cv = cosf(ang);
  float scale = isq ? (1.4426950408889634f * 0.08838834764831845f) : 1.0f;
  float o1 = (x1 * cv + x2 * sv) * rinv * scale;
  float o2 = (x2 * cv - x1 * sv) * rinv * scale;
  __hip_bfloat16* dst = isq ? q_l + ((size_t)(b * NH + h) * TT + t) * HD
                            : k_l + ((size_t)(b * NKV + h) * TT + t) * HD;
  *(unsigned short*)(dst + lane) = (unsigned short)bfbits(o1);
  *(unsigned short*)(dst + lane + 64) = (unsigned short)bfbits(o2);
}

// ---------- V transpose: qkv v-cols -> vt[b][hk][d][t] ----------
__global__ __launch_bounds__(256) void k_vtrans(const __hip_bfloat16* __restrict__ qkv,
                                                __hip_bfloat16* __restrict__ vt) {
  __shared__ __hip_bfloat16 tile[64][130];
  int bid = blockIdx.x;
  int t0 = (bid & 31) * 64;
  int hk = (bid >> 5) & 3;
  int b = bid >> 7;
  int tid = threadIdx.x;
#pragma unroll
  for (int j = 0; j < 32; j++) {
    int e = j * 256 + tid;
    int tt = e >> 7, d = e & 127;
    tile[tt][d] = qkv[(size_t)(b * TT + t0 + tt) * NQKV + NQ + NK + hk * HD + d];
  }
  __syncthreads();
#pragma unroll
  for (int j = 0; j < 32; j++) {
    int e = j * 256 + tid;
    int d = e >> 6, tt = e & 63;
    vt[(((size_t)(b * NKV + hk)) * HD + d) * TT + t0 + tt] = tile[tt][d];
  }
}

// ---------- flash attention v2 (causal, GQA) ----------
// Pair-balanced: block p handles q-tiles p and 31-p (uniform 33 iters).
// K/V double-buffered via cross-iteration global_load_lds prefetch.
// Q frags wave-private in registers (no Q LDS).
__global__ __launch_bounds__(256, 2) void k_attn(
    const __hip_bfloat16* __restrict__ q_l, const __hip_bfloat16* __restrict__ k_l,
    const __hip_bfloat16* __restrict__ vt_l, __hip_bfloat16* __restrict__ y) {
  __shared__ __align__(16) __hip_bfloat16 Ks[2][64 * 128];
  __shared__ __align__(16) __hip_bfloat16 Vs[2][128 * 64];
  const int tid = threadIdx.x, lane = tid & 63, w = tid >> 6;
  const int q15 = lane & 15, quad = lane >> 4;
  const int p = blockIdx.x;  // pair index 0..15
  const int h = blockIdx.y, b = blockIdx.z;
  const int hk = h >> 2;

  const __hip_bfloat16* kbase = k_l + (size_t)(b * NKV + hk) * TT * HD;
  const __hip_bfloat16* vbase = vt_l + (size_t)(b * NKV + hk) * HD * TT;

  auto stage = [&](int kb, int buf) {
#pragma unroll
    for (int i = 0; i < 4; i++) {
      int s = i * 256 + tid;
      int rk = s >> 4, ck = s & 15;
      gl_lds16(kbase + (size_t)(kb * 64 + rk) * HD + (ck ^ (rk & 15)) * 8,
               Ks[buf] + (i * 256 + (tid & ~63)) * 8);
      int rv = s >> 3, cv = s & 7;
      gl_lds16(vbase + (size_t)rv * TT + kb * 64 + (cv ^ (rv & 7)) * 8,
               Vs[buf] + (i * 256 + (tid & ~63)) * 8);
    }
  };

  const int s0lane = ((quad & 1) << 1) * 16 + q15;
  const int s1lane = s0lane + 16;
  const bool hi = quad >= 2;
  int cur = 0;

  for (int ph = 0; ph < 2; ph++) {
    const int qb = ph ? (TT / 64 - 1 - p) : p;
    const __hip_bfloat16* qbase = q_l + ((size_t)(b * NH + h) * TT + qb * 64) * HD;

    bf16x8 qf[4];
#pragma unroll
    for (int dc = 0; dc < 4; dc++)
      qf[dc] = *(const bf16x8*)(qbase + (size_t)(w * 16 + q15) * HD + dc * 32 + quad * 8);

    floatx4 ot[8] = {};
    float m_run = -INFINITY, l_run = 0.0f;

    for (int kb = 0; kb <= qb; kb++) {
      __syncthreads();  // drains vmcnt: cur-buffer loads (issued last iter) complete
      if (kb == 0) {    // phase prologue: synchronous first stage
        stage(0, cur);
        __syncthreads();
      }
      if (kb < qb) stage(kb + 1, cur ^ 1);  // prefetch, drained at NEXT barrier

      // S^T = K @ Q^T
      floatx4 st[4] = {};
#pragma unroll
      for (int kt = 0; kt < 4; kt++) {
        int r = kt * 16 + q15;
#pragma unroll
        for (int dc = 0; dc < 4; dc++) {
          int c = dc * 4 + quad;
          bf16x8 kf = *(const bf16x8*)(Ks[cur] + (r * 16 + (c ^ (r & 15))) * 8);
          st[kt] = mfma16(kf, qf[dc], st[kt]);
        }
      }
      if (kb == qb) {  // causal mask on diagonal block
        int qg = w * 16 + q15;
#pragma unroll
        for (int kt = 0; kt < 4; kt++)
#pragma unroll
          for (int r = 0; r < 4; r++)
            if (kt * 16 + quad * 4 + r > qg) st[kt][r] = -INFINITY;
      }
      // online softmax (q-row == lane&15; keys across regs + quads)
      float mloc = -INFINITY;
#pragma unroll
      for (int kt = 0; kt < 4; kt++)
#pragma unroll
        for (int r = 0; r < 4; r++) mloc = fmaxf(mloc, st[kt][r]);
      mloc = fmaxf(mloc, __shfl_xor(mloc, 16, 64));
      mloc = fmaxf(mloc, __shfl_xor(mloc, 32, 64));
      float m_new = fmaxf(m_run, mloc);
      float rsum = 0.f;
      int pk[4][2];
#pragma unroll
      for (int kt = 0; kt < 4; kt++) {
        float p0 = exp2f(st[kt][0] - m_new);
        float p1 = exp2f(st[kt][1] - m_new);
        float p2 = exp2f(st[kt][2] - m_new);
        float p3 = exp2f(st[kt][3] - m_new);
        rsum += (p0 + p1) + (p2 + p3);
        pk[kt][0] = pack2bf(p0, p1);
        pk[kt][1] = pack2bf(p2, p3);
      }
      rsum += __shfl_xor(rsum, 16, 64);
      rsum += __shfl_xor(rsum, 32, 64);
      if (__any(m_new > m_run)) {  // rescale only when some lane's max moved
        float alpha = exp2f(m_run - m_new);
        l_run *= alpha;
#pragma unroll
        for (int dt = 0; dt < 8; dt++) {
          ot[dt][0] *= alpha; ot[dt][1] *= alpha;
          ot[dt][2] *= alpha; ot[dt][3] *= alpha;
        }
      }
      l_run += rsum;
      m_run = m_new;

      // P^T (C-layout) -> B-operand frags via shuffles, then PV
#pragma unroll
      for (int kc = 0; kc < 2; kc++) {
        int lo0 = __shfl(pk[kc * 2][0], s0lane, 64);
        int lo1 = __shfl(pk[kc * 2][1], s0lane, 64);
        int lo2 = __shfl(pk[kc * 2][0], s1lane, 64);
        int lo3 = __shfl(pk[kc * 2][1], s1lane, 64);
        int h0 = __shfl(pk[kc * 2 + 1][0], s0lane, 64);
        int h1 = __shfl(pk[kc * 2 + 1][1], s0lane, 64);
        int h2 = __shfl(pk[kc * 2 + 1][0], s1lane, 64);
        int h3 = __shfl(pk[kc * 2 + 1][1], s1lane, 64);
        union { int i[4]; bf16x8 v; } pu;
        pu.i[0] = hi ? h0 : lo0;
        pu.i[1] = hi ? h1 : lo1;
        pu.i[2] = hi ? h2 : lo2;
        pu.i[3] = hi ? h3 : lo3;
        bf16x8 pf = pu.v;
#pragma unroll
        for (int dt = 0; dt < 8; dt++) {
          int r = dt * 16 + q15, c = kc * 4 + quad;
          bf16x8 vf = *(const bf16x8*)(Vs[cur] + (r * 8 + (c ^ (r & 7))) * 8);
          ot[dt] = mfma16(vf, pf, ot[dt]);  // y^T[d][q]
        }
      }
      cur ^= 1;
    }
    // epilogue: y[b][t][h*128+d]
    float linv = 1.0f / l_run;
    int t = qb * 64 + w * 16 + q15;
    __hip_bfloat16* yrow = y + (size_t)(b * TT + t) * TC + h * HD;
#pragma unroll
    for (int dt = 0; dt < 8; dt++) {
      int d = dt * 16 + quad * 4;
      ushort4 o;
      o.x = (unsigned short)bfbits(ot[dt][0] * linv);
      o.y = (unsigned short)bfbits(ot[dt][1] * linv);
      o.z = (unsigned short)bfbits(ot[dt][2] * linv);
      o.w = (unsigned short)bfbits(ot[dt][3] * linv);
      *(ushort4*)(yrow + d) = o;
    }
  }
}

// ---------- launcher ----------
extern "C" void kernel_launch(void* const* d_in, const int* in_sizes, int n_in,
                              void* d_out, int out_size, void* d_ws, size_t ws_size,
                              hipStream_t stream) {
  (void)in_sizes; (void)n_in; (void)out_size; (void)ws_size;
  const float* x  = (const float*)d_in[0];
  const float* Wq = (const float*)d_in[1];
  const float* Wk = (const float*)d_in[2];
  const float* Wv = (const float*)d_in[3];
  const float* Wo = (const float*)d_in[4];
  float* out = (float*)d_out;

  char* ws = (char*)d_ws;
  size_t off = 0;
  auto alloc = [&](size_t bytes) {
    void* p = ws + off;
    off += (bytes + 255) & ~(size_t)255;
    return p;
  };
  __hip_bfloat16* xb   = (__hip_bfloat16*)alloc((size_t)MR * TC * 2);
  __hip_bfloat16* wqkv = (__hip_bfloat16*)alloc((size_t)NQKV * TC * 2);
  __hip_bfloat16* wo   = (__hip_bfloat16*)alloc((size_t)TC * TC * 2);
  __hip_bfloat16* qkv  = (__hip_bfloat16*)alloc((size_t)MR * NQKV * 2);
  __hip_bfloat16* q_l  = (__hip_bfloat16*)alloc((size_t)TB * NH * TT * HD * 2);
  __hip_bfloat16* k_l  = (__hip_bfloat16*)alloc((size_t)TB * NKV * TT * HD * 2);
  __hip_bfloat16* vt_l = (__hip_bfloat16*)alloc((size_t)TB * NKV * HD * TT * 2);
  __hip_bfloat16* yb   = (__hip_bfloat16*)alloc((size_t)MR * TC * 2);

  // all 5 fp32->bf16 converts in one launch
  k_cvt5<<<dim3((MR * TC / 4 + 255) / 256, 5), 256, 0, stream>>>(
      x, Wq, Wk, Wv, Wo,
      xb, wqkv, wqkv + (size_t)NQ * TC, wqkv + (size_t)(NQ + NK) * TC, wo);

  // fused QKV projection: [4096,3072] = xb @ wqkv^T
  k_gemm_bt<__hip_bfloat16><<<dim3(NQKV / 128, MR / 128), 256, 0, stream>>>(
      xb, wqkv, qkv, MR, NQKV, TC);

  k_ropenorm<<<(MR * 20) / 4, 256, 0, stream>>>(qkv, q_l, k_l);
  k_vtrans<<<TB * NKV * (TT / 64), 256, 0, stream>>>(qkv, vt_l);

  // flash attention (pair-balanced grid: 16 pairs x 16 heads x 2 batch)
  k_attn<<<dim3(TT / 64 / 2, NH, TB), 256, 0, stream>>>(q_l, k_l, vt_l, yb);

  // output projection (fp32 out)
  k_gemm_bt<float><<<dim3(TC / 128, MR / 128), 256, 0, stream>>>(
      yb, wo, out, MR, TC, TC);
}

// Round 3
// 320.561 us; speedup vs baseline: 1.2407x; 1.0322x over previous
//
#include <hip/hip_runtime.h>
#include <hip/hip_bf16.h>
#include <cstdint>
#include <math.h>

#define DEVINL __device__ __forceinline__

typedef __attribute__((ext_vector_type(8))) __bf16 bf16x8;
typedef __attribute__((ext_vector_type(4))) float floatx4;

constexpr int TB = 2;        // batch
constexpr int TT = 2048;     // seq len
constexpr int TC = 2048;     // channels
constexpr int NH = 16, NKV = 4, HD = 128;
constexpr int MR = TB * TT;           // 4096 token rows
constexpr int NQ = NH * HD;           // 2048
constexpr int NK = NKV * HD;          // 512
constexpr int NQKV = NQ + 2 * NK;     // 3072

// ---------- helpers ----------
DEVINL unsigned bfbits(float f) {  // fp32 -> bf16 bits, RNE
  unsigned u = __builtin_bit_cast(unsigned, f);
  return (u + 0x7FFFu + ((u >> 16) & 1u)) >> 16;
}
DEVINL int pk2(float a, float b) {  // packed fp32x2 -> bf16x2 (v_cvt_pk_bf16_f32)
  union { __hip_bfloat162 h; int i; } u;
  u.h = __float22bfloat162_rn(float2{a, b});
  return u.i;
}
DEVINL void gl_lds16(const __hip_bfloat16* g, __hip_bfloat16* l) {
  __builtin_amdgcn_global_load_lds(
      (const __attribute__((address_space(1))) unsigned int*)g,
      (__attribute__((address_space(3))) unsigned int*)l, 16, 0, 0);
}
DEVINL floatx4 mfma16(bf16x8 a, bf16x8 b, floatx4 c) {
  return __builtin_amdgcn_mfma_f32_16x16x32_bf16(a, b, c, 0, 0, 0);
}
DEVINL void cstore(float* p, float v) { *p = v; }
DEVINL void cstore(__hip_bfloat16* p, float v) { *(unsigned short*)p = (unsigned short)bfbits(v); }

// ---------- fused fp32 -> bf16 convert (all 5 inputs, one launch) ----------
__global__ __launch_bounds__(256) void k_cvt5(
    const float* __restrict__ s0, const float* __restrict__ s1,
    const float* __restrict__ s2, const float* __restrict__ s3,
    const float* __restrict__ s4,
    __hip_bfloat16* __restrict__ d0, __hip_bfloat16* __restrict__ d1,
    __hip_bfloat16* __restrict__ d2, __hip_bfloat16* __restrict__ d3,
    __hip_bfloat16* __restrict__ d4) {
  const float* s;
  __hip_bfloat16* d;
  int n;
  switch (blockIdx.y) {
    case 0: s = s0; d = d0; n = MR * TC; break;
    case 1: s = s1; d = d1; n = NQ * TC; break;
    case 2: s = s2; d = d2; n = NK * TC; break;
    case 3: s = s3; d = d3; n = NK * TC; break;
    default: s = s4; d = d4; n = TC * TC; break;
  }
  int i = (blockIdx.x * 256 + threadIdx.x) * 4;
  if (i >= n) return;
  float4 v = *(const float4*)(s + i);
  ushort4 o;
  o.x = (unsigned short)bfbits(v.x);
  o.y = (unsigned short)bfbits(v.y);
  o.z = (unsigned short)bfbits(v.z);
  o.w = (unsigned short)bfbits(v.w);
  *(ushort4*)(d + i) = o;
}

// ---------- GEMM: C[M,N] = A[M,K] @ B[N,K]^T  (m97 structure) ----------
template <typename OUT_T>
__global__ __launch_bounds__(256, 2) void k_gemm_bt(
    const __hip_bfloat16* __restrict__ A, const __hip_bfloat16* __restrict__ B,
    OUT_T* __restrict__ C, int M, int N, int K) {
  __shared__ __align__(16) __hip_bfloat16 As[128 * 32];
  __shared__ __align__(16) __hip_bfloat16 Bs[128 * 32];
  const int tid = threadIdx.x;
  const int lane = tid & 63, w = tid >> 6;
  const int q15 = lane & 15, quad = lane >> 4;
  const int wm = w >> 1, wn = w & 1;
  const int tm = blockIdx.y, tn = blockIdx.x;

  const int r0 = tid >> 2, c0 = (tid & 3) * 8;
  const __hip_bfloat16* a0 = A + (size_t)(tm * 128 + r0) * K + c0;
  const __hip_bfloat16* a1 = A + (size_t)(tm * 128 + r0 + 64) * K + c0;
  const __hip_bfloat16* b0 = B + (size_t)(tn * 128 + r0) * K + c0;
  const __hip_bfloat16* b1 = B + (size_t)(tn * 128 + r0 + 64) * K + c0;
  __hip_bfloat16* lA0 = As + (tid & ~63) * 8;
  __hip_bfloat16* lA1 = As + 2048 + (tid & ~63) * 8;
  __hip_bfloat16* lB0 = Bs + (tid & ~63) * 8;
  __hip_bfloat16* lB1 = Bs + 2048 + (tid & ~63) * 8;

  floatx4 acc[4][4] = {};
  for (int k0 = 0; k0 < K; k0 += 32) {
    __syncthreads();
    gl_lds16(a0 + k0, lA0);
    gl_lds16(a1 + k0, lA1);
    gl_lds16(b0 + k0, lB0);
    gl_lds16(b1 + k0, lB1);
    __syncthreads();
    bf16x8 af[4], bfr[4];
#pragma unroll
    for (int i = 0; i < 4; i++)
      af[i] = *(const bf16x8*)(As + (wm * 64 + i * 16 + q15) * 32 + quad * 8);
#pragma unroll
    for (int i = 0; i < 4; i++)
      bfr[i] = *(const bf16x8*)(Bs + (wn * 64 + i * 16 + q15) * 32 + quad * 8);
#pragma unroll
    for (int mi = 0; mi < 4; mi++)
#pragma unroll
      for (int ni = 0; ni < 4; ni++)
        acc[mi][ni] = mfma16(af[mi], bfr[ni], acc[mi][ni]);
  }
#pragma unroll
  for (int mi = 0; mi < 4; mi++) {
    int row0 = tm * 128 + wm * 64 + mi * 16 + quad * 4;
#pragma unroll
    for (int ni = 0; ni < 4; ni++) {
      int col = tn * 128 + wn * 64 + ni * 16 + q15;
#pragma unroll
      for (int r = 0; r < 4; r++)
        cstore(C + (size_t)(row0 + r) * N + col, acc[mi][ni][r]);
    }
  }
}

// ---------- fused (RMSNorm + RoPE + layout) and V-transpose, one launch ----------
constexpr int ROPE_BLOCKS = (MR * 20) / 4;  // 20480
__global__ __launch_bounds__(256) void k_prep(
    const __hip_bfloat16* __restrict__ qkv,
    __hip_bfloat16* __restrict__ q_l, __hip_bfloat16* __restrict__ k_l,
    __hip_bfloat16* __restrict__ vt) {
  if (blockIdx.x < ROPE_BLOCKS) {
    int gw = (blockIdx.x * 256 + threadIdx.x) >> 6;
    int lane = threadIdx.x & 63;
    int head = gw % 20;
    int bt = gw / 20;
    int b = bt >> 11, t = bt & (TT - 1);
    bool isq = head < NH;
    int h = isq ? head : head - NH;
    const __hip_bfloat16* src = qkv + (size_t)bt * NQKV + (isq ? h * HD : NQ + h * HD);
    float x1 = __bfloat162float(src[lane]);
    float x2 = __bfloat162float(src[lane + 64]);
    float ss = x1 * x1 + x2 * x2;
#pragma unroll
    for (int m = 1; m < 64; m <<= 1) ss += __shfl_xor(ss, m, 64);
    float rinv = rsqrtf(ss * (1.0f / 128.0f) + 1.1920928955078125e-07f);
    float ang = (float)t * exp2f((float)lane * -(13.287712379549449f / 64.0f));
    float sv = sinf(ang), cv = cosf(ang);
    float scale = isq ? (1.4426950408889634f * 0.08838834764831845f) : 1.0f;
    float o1 = (x1 * cv + x2 * sv) * rinv * scale;
    float o2 = (x2 * cv - x1 * sv) * rinv * scale;
    __hip_bfloat16* dst = isq ? q_l + ((size_t)(b * NH + h) * TT + t) * HD
                              : k_l + ((size_t)(b * NKV + h) * TT + t) * HD;
    *(unsigned short*)(dst + lane) = (unsigned short)bfbits(o1);
    *(unsigned short*)(dst + lane + 64) = (unsigned short)bfbits(o2);
  } else {
    __shared__ __hip_bfloat16 tile[64][130];
    int bid = blockIdx.x - ROPE_BLOCKS;
    int t0 = (bid & 31) * 64;
    int hk = (bid >> 5) & 3;
    int b = bid >> 7;
    int tid = threadIdx.x;
#pragma unroll
    for (int j = 0; j < 32; j++) {
      int e = j * 256 + tid;
      int tt = e >> 7, d = e & 127;
      tile[tt][d] = qkv[(size_t)(b * TT + t0 + tt) * NQKV + NQ + NK + hk * HD + d];
    }
    __syncthreads();
#pragma unroll
    for (int j = 0; j < 32; j++) {
      int e = j * 256 + tid;
      int d = e >> 6, tt = e & 63;
      vt[(((size_t)(b * NKV + hk)) * HD + d) * TT + t0 + tt] = tile[tt][d];
    }
  }
}

// ---------- flash attention v3 (causal, GQA) ----------
// Static-max softmax: RMS-normed q,k give |s*log2e/sqrt(128)| <= 16.34, so
// exp2(s) never overflows/underflows -- no online max, no alpha rescale.
// Pair-balanced blocks, K/V dbuf cross-iteration prefetch, reg-resident Q.
__global__ __launch_bounds__(256, 2) void k_attn(
    const __hip_bfloat16* __restrict__ q_l, const __hip_bfloat16* __restrict__ k_l,
    const __hip_bfloat16* __restrict__ vt_l, __hip_bfloat16* __restrict__ y) {
  __shared__ __align__(16) __hip_bfloat16 Ks[2][64 * 128];
  __shared__ __align__(16) __hip_bfloat16 Vs[2][128 * 64];
  const int tid = threadIdx.x, lane = tid & 63, w = tid >> 6;
  const int q15 = lane & 15, quad = lane >> 4;
  const int p = blockIdx.x;
  const int h = blockIdx.y, b = blockIdx.z;
  const int hk = h >> 2;

  const __hip_bfloat16* kbase = k_l + (size_t)(b * NKV + hk) * TT * HD;
  const __hip_bfloat16* vbase = vt_l + (size_t)(b * NKV + hk) * HD * TT;

  auto stage = [&](int kb, int buf) {
#pragma unroll
    for (int i = 0; i < 4; i++) {
      int s = i * 256 + tid;
      int rk = s >> 4, ck = s & 15;
      gl_lds16(kbase + (size_t)(kb * 64 + rk) * HD + (ck ^ (rk & 15)) * 8,
               Ks[buf] + (i * 256 + (tid & ~63)) * 8);
      int rv = s >> 3, cv = s & 7;
      gl_lds16(vbase + (size_t)rv * TT + kb * 64 + (cv ^ (rv & 7)) * 8,
               Vs[buf] + (i * 256 + (tid & ~63)) * 8);
    }
  };

  const int s0lane = ((quad & 1) << 1) * 16 + q15;
  const int s1lane = s0lane + 16;
  const bool hi = quad >= 2;
  int cur = 0;

  for (int ph = 0; ph < 2; ph++) {
    const int qb = ph ? (TT / 64 - 1 - p) : p;
    const __hip_bfloat16* qbase = q_l + ((size_t)(b * NH + h) * TT + qb * 64) * HD;

    bf16x8 qf[4];
#pragma unroll
    for (int dc = 0; dc < 4; dc++)
      qf[dc] = *(const bf16x8*)(qbase + (size_t)(w * 16 + q15) * HD + dc * 32 + quad * 8);

    floatx4 ot[8] = {};
    float lsum = 0.0f;  // per-lane partial of sum(p); cross-quad reduce deferred

    for (int kb = 0; kb <= qb; kb++) {
      __syncthreads();  // drains vmcnt: cur-buffer loads complete
      if (kb == 0) {
        stage(0, cur);
        __syncthreads();
      }
      if (kb < qb) stage(kb + 1, cur ^ 1);

      // S^T = K @ Q^T
      floatx4 st[4] = {};
#pragma unroll
      for (int kt = 0; kt < 4; kt++) {
        int r = kt * 16 + q15;
#pragma unroll
        for (int dc = 0; dc < 4; dc++) {
          int c = dc * 4 + quad;
          bf16x8 kf = *(const bf16x8*)(Ks[cur] + (r * 16 + (c ^ (r & 15))) * 8);
          st[kt] = mfma16(kf, qf[dc], st[kt]);
        }
      }
      if (kb == qb) {  // causal mask on diagonal block
        int qg = w * 16 + q15;
#pragma unroll
        for (int kt = 0; kt < 4; kt++)
#pragma unroll
          for (int r = 0; r < 4; r++)
            if (kt * 16 + quad * 4 + r > qg) st[kt][r] = -INFINITY;
      }
      // static-max softmax: p = exp2(s) directly
      int pk[4][2];
#pragma unroll
      for (int kt = 0; kt < 4; kt++) {
        float p0 = exp2f(st[kt][0]);
        float p1 = exp2f(st[kt][1]);
        float p2 = exp2f(st[kt][2]);
        float p3 = exp2f(st[kt][3]);
        lsum += (p0 + p1) + (p2 + p3);
        pk[kt][0] = pk2(p0, p1);
        pk[kt][1] = pk2(p2, p3);
      }
      // P^T (C-layout) -> B-operand frags via shuffles, then PV
#pragma unroll
      for (int kc = 0; kc < 2; kc++) {
        int lo0 = __shfl(pk[kc * 2][0], s0lane, 64);
        int lo1 = __shfl(pk[kc * 2][1], s0lane, 64);
        int lo2 = __shfl(pk[kc * 2][0], s1lane, 64);
        int lo3 = __shfl(pk[kc * 2][1], s1lane, 64);
        int h0 = __shfl(pk[kc * 2 + 1][0], s0lane, 64);
        int h1 = __shfl(pk[kc * 2 + 1][1], s0lane, 64);
        int h2 = __shfl(pk[kc * 2 + 1][0], s1lane, 64);
        int h3 = __shfl(pk[kc * 2 + 1][1], s1lane, 64);
        union { int i[4]; bf16x8 v; } pu;
        pu.i[0] = hi ? h0 : lo0;
        pu.i[1] = hi ? h1 : lo1;
        pu.i[2] = hi ? h2 : lo2;
        pu.i[3] = hi ? h3 : lo3;
        bf16x8 pf = pu.v;
#pragma unroll
        for (int dt = 0; dt < 8; dt++) {
          int r = dt * 16 + q15, c = kc * 4 + quad;
          bf16x8 vf = *(const bf16x8*)(Vs[cur] + (r * 8 + (c ^ (r & 7))) * 8);
          ot[dt] = mfma16(vf, pf, ot[dt]);  // y^T[d][q]
        }
      }
      cur ^= 1;
    }
    // reduce l across quads (each lane's partial covers its quad's key subset)
    lsum += __shfl_xor(lsum, 16, 64);
    lsum += __shfl_xor(lsum, 32, 64);
    float linv = 1.0f / lsum;
    int t = qb * 64 + w * 16 + q15;
    __hip_bfloat16* yrow = y + (size_t)(b * TT + t) * TC + h * HD;
#pragma unroll
    for (int dt = 0; dt < 8; dt++) {
      int d = dt * 16 + quad * 4;
      ushort4 o;
      o.x = (unsigned short)bfbits(ot[dt][0] * linv);
      o.y = (unsigned short)bfbits(ot[dt][1] * linv);
      o.z = (unsigned short)bfbits(ot[dt][2] * linv);
      o.w = (unsigned short)bfbits(ot[dt][3] * linv);
      *(ushort4*)(yrow + d) = o;
    }
  }
}

// ---------- launcher ----------
extern "C" void kernel_launch(void* const* d_in, const int* in_sizes, int n_in,
                              void* d_out, int out_size, void* d_ws, size_t ws_size,
                              hipStream_t stream) {
  (void)in_sizes; (void)n_in; (void)out_size; (void)ws_size;
  const float* x  = (const float*)d_in[0];
  const float* Wq = (const float*)d_in[1];
  const float* Wk = (const float*)d_in[2];
  const float* Wv = (const float*)d_in[3];
  const float* Wo = (const float*)d_in[4];
  float* out = (float*)d_out;

  char* ws = (char*)d_ws;
  size_t off = 0;
  auto alloc = [&](size_t bytes) {
    void* p = ws + off;
    off += (bytes + 255) & ~(size_t)255;
    return p;
  };
  __hip_bfloat16* xb   = (__hip_bfloat16*)alloc((size_t)MR * TC * 2);
  __hip_bfloat16* wqkv = (__hip_bfloat16*)alloc((size_t)NQKV * TC * 2);
  __hip_bfloat16* wo   = (__hip_bfloat16*)alloc((size_t)TC * TC * 2);
  __hip_bfloat16* qkv  = (__hip_bfloat16*)alloc((size_t)MR * NQKV * 2);
  __hip_bfloat16* q_l  = (__hip_bfloat16*)alloc((size_t)TB * NH * TT * HD * 2);
  __hip_bfloat16* k_l  = (__hip_bfloat16*)alloc((size_t)TB * NKV * TT * HD * 2);
  __hip_bfloat16* vt_l = (__hip_bfloat16*)alloc((size_t)TB * NKV * HD * TT * 2);
  __hip_bfloat16* yb   = (__hip_bfloat16*)alloc((size_t)MR * TC * 2);

  k_cvt5<<<dim3((MR * TC / 4 + 255) / 256, 5), 256, 0, stream>>>(
      x, Wq, Wk, Wv, Wo,
      xb, wqkv, wqkv + (size_t)NQ * TC, wqkv + (size_t)(NQ + NK) * TC, wo);

  k_gemm_bt<__hip_bfloat16><<<dim3(NQKV / 128, MR / 128), 256, 0, stream>>>(
      xb, wqkv, qkv, MR, NQKV, TC);

  k_prep<<<ROPE_BLOCKS + TB * NKV * (TT / 64), 256, 0, stream>>>(qkv, q_l, k_l, vt_l);

  k_attn<<<dim3(TT / 64 / 2, NH, TB), 256, 0, stream>>>(q_l, k_l, vt_l, yb);

  k_gemm_bt<float><<<dim3(TC / 128, MR / 128), 256, 0, stream>>>(
      yb, wo, out, MR, TC, TC);
}

// Round 4
// 319.301 us; speedup vs baseline: 1.2456x; 1.0039x over previous
//
#include <hip/hip_runtime.h>
#include <hip/hip_bf16.h>
#include <cstdint>
#include <math.h>

#define DEVINL __device__ __forceinline__

typedef __attribute__((ext_vector_type(8))) __bf16 bf16x8;
typedef __attribute__((ext_vector_type(4))) float floatx4;

constexpr int TB = 2;        // batch
constexpr int TT = 2048;     // seq len
constexpr int TC = 2048;     // channels
constexpr int NH = 16, NKV = 4, HD = 128;
constexpr int MR = TB * TT;           // 4096 token rows
constexpr int NQ = NH * HD;           // 2048
constexpr int NK = NKV * HD;          // 512
constexpr int NQKV = NQ + 2 * NK;     // 3072

// ---------- helpers ----------
DEVINL unsigned bfbits(float f) {  // fp32 -> bf16 bits, RNE
  unsigned u = __builtin_bit_cast(unsigned, f);
  return (u + 0x7FFFu + ((u >> 16) & 1u)) >> 16;
}
DEVINL int pk2(float a, float b) {  // packed fp32x2 -> bf16x2 (v_cvt_pk_bf16_f32)
  union { __hip_bfloat162 h; int i; } u;
  u.h = __float22bfloat162_rn(float2{a, b});
  return u.i;
}
DEVINL void gl_lds16(const __hip_bfloat16* g, __hip_bfloat16* l) {
  __builtin_amdgcn_global_load_lds(
      (const __attribute__((address_space(1))) unsigned int*)g,
      (__attribute__((address_space(3))) unsigned int*)l, 16, 0, 0);
}
DEVINL floatx4 mfma16(bf16x8 a, bf16x8 b, floatx4 c) {
  return __builtin_amdgcn_mfma_f32_16x16x32_bf16(a, b, c, 0, 0, 0);
}
DEVINL void cstore(float* p, float v) { *p = v; }
DEVINL void cstore(__hip_bfloat16* p, float v) { *(unsigned short*)p = (unsigned short)bfbits(v); }

// ---------- fused fp32 -> bf16 convert (all 5 inputs, one launch) ----------
__global__ __launch_bounds__(256) void k_cvt5(
    const float* __restrict__ s0, const float* __restrict__ s1,
    const float* __restrict__ s2, const float* __restrict__ s3,
    const float* __restrict__ s4,
    __hip_bfloat16* __restrict__ d0, __hip_bfloat16* __restrict__ d1,
    __hip_bfloat16* __restrict__ d2, __hip_bfloat16* __restrict__ d3,
    __hip_bfloat16* __restrict__ d4) {
  const float* s;
  __hip_bfloat16* d;
  int n;
  switch (blockIdx.y) {
    case 0: s = s0; d = d0; n = MR * TC; break;
    case 1: s = s1; d = d1; n = NQ * TC; break;
    case 2: s = s2; d = d2; n = NK * TC; break;
    case 3: s = s3; d = d3; n = NK * TC; break;
    default: s = s4; d = d4; n = TC * TC; break;
  }
  int i = (blockIdx.x * 256 + threadIdx.x) * 4;
  if (i >= n) return;
  float4 v = *(const float4*)(s + i);
  ushort4 o;
  o.x = (unsigned short)bfbits(v.x);
  o.y = (unsigned short)bfbits(v.y);
  o.z = (unsigned short)bfbits(v.z);
  o.w = (unsigned short)bfbits(v.w);
  *(ushort4*)(d + i) = o;
}

// ---------- GEMM: C[M,N] = A[M,K] @ B[N,K]^T  (m97 structure) ----------
template <typename OUT_T>
__global__ __launch_bounds__(256, 2) void k_gemm_bt(
    const __hip_bfloat16* __restrict__ A, const __hip_bfloat16* __restrict__ B,
    OUT_T* __restrict__ C, int M, int N, int K) {
  __shared__ __align__(16) __hip_bfloat16 As[128 * 32];
  __shared__ __align__(16) __hip_bfloat16 Bs[128 * 32];
  const int tid = threadIdx.x;
  const int lane = tid & 63, w = tid >> 6;
  const int q15 = lane & 15, quad = lane >> 4;
  const int wm = w >> 1, wn = w & 1;
  const int tm = blockIdx.y, tn = blockIdx.x;

  const int r0 = tid >> 2, c0 = (tid & 3) * 8;
  const __hip_bfloat16* a0 = A + (size_t)(tm * 128 + r0) * K + c0;
  const __hip_bfloat16* a1 = A + (size_t)(tm * 128 + r0 + 64) * K + c0;
  const __hip_bfloat16* b0 = B + (size_t)(tn * 128 + r0) * K + c0;
  const __hip_bfloat16* b1 = B + (size_t)(tn * 128 + r0 + 64) * K + c0;
  __hip_bfloat16* lA0 = As + (tid & ~63) * 8;
  __hip_bfloat16* lA1 = As + 2048 + (tid & ~63) * 8;
  __hip_bfloat16* lB0 = Bs + (tid & ~63) * 8;
  __hip_bfloat16* lB1 = Bs + 2048 + (tid & ~63) * 8;

  floatx4 acc[4][4] = {};
  for (int k0 = 0; k0 < K; k0 += 32) {
    __syncthreads();
    gl_lds16(a0 + k0, lA0);
    gl_lds16(a1 + k0, lA1);
    gl_lds16(b0 + k0, lB0);
    gl_lds16(b1 + k0, lB1);
    __syncthreads();
    bf16x8 af[4], bfr[4];
#pragma unroll
    for (int i = 0; i < 4; i++)
      af[i] = *(const bf16x8*)(As + (wm * 64 + i * 16 + q15) * 32 + quad * 8);
#pragma unroll
    for (int i = 0; i < 4; i++)
      bfr[i] = *(const bf16x8*)(Bs + (wn * 64 + i * 16 + q15) * 32 + quad * 8);
#pragma unroll
    for (int mi = 0; mi < 4; mi++)
#pragma unroll
      for (int ni = 0; ni < 4; ni++)
        acc[mi][ni] = mfma16(af[mi], bfr[ni], acc[mi][ni]);
  }
#pragma unroll
  for (int mi = 0; mi < 4; mi++) {
    int row0 = tm * 128 + wm * 64 + mi * 16 + quad * 4;
#pragma unroll
    for (int ni = 0; ni < 4; ni++) {
      int col = tn * 128 + wn * 64 + ni * 16 + q15;
#pragma unroll
      for (int r = 0; r < 4; r++)
        cstore(C + (size_t)(row0 + r) * N + col, acc[mi][ni][r]);
    }
  }
}

// ---------- fused (RMSNorm + RoPE + layout) and V-transpose, one launch ----------
constexpr int ROPE_BLOCKS = (MR * 20) / 4;  // 20480
__global__ __launch_bounds__(256) void k_prep(
    const __hip_bfloat16* __restrict__ qkv,
    __hip_bfloat16* __restrict__ q_l, __hip_bfloat16* __restrict__ k_l,
    __hip_bfloat16* __restrict__ vt) {
  if (blockIdx.x < ROPE_BLOCKS) {
    int gw = (blockIdx.x * 256 + threadIdx.x) >> 6;
    int lane = threadIdx.x & 63;
    int head = gw % 20;
    int bt = gw / 20;
    int b = bt >> 11, t = bt & (TT - 1);
    bool isq = head < NH;
    int h = isq ? head : head - NH;
    const __hip_bfloat16* src = qkv + (size_t)bt * NQKV + (isq ? h * HD : NQ + h * HD);
    float x1 = __bfloat162float(src[lane]);
    float x2 = __bfloat162float(src[lane + 64]);
    float ss = x1 * x1 + x2 * x2;
#pragma unroll
    for (int m = 1; m < 64; m <<= 1) ss += __shfl_xor(ss, m, 64);
    float rinv = rsqrtf(ss * (1.0f / 128.0f) + 1.1920928955078125e-07f);
    float ang = (float)t * exp2f((float)lane * -(13.287712379549449f / 64.0f));
    float sv = sinf(ang), cv = cosf(ang);
    float scale = isq ? (1.4426950408889634f * 0.08838834764831845f) : 1.0f;
    float o1 = (x1 * cv + x2 * sv) * rinv * scale;
    float o2 = (x2 * cv - x1 * sv) * rinv * scale;
    __hip_bfloat16* dst = isq ? q_l + ((size_t)(b * NH + h) * TT + t) * HD
                              : k_l + ((size_t)(b * NKV + h) * TT + t) * HD;
    *(unsigned short*)(dst + lane) = (unsigned short)bfbits(o1);
    *(unsigned short*)(dst + lane + 64) = (unsigned short)bfbits(o2);
  } else {
    __shared__ __hip_bfloat16 tile[64][130];
    int bid = blockIdx.x - ROPE_BLOCKS;
    int t0 = (bid & 31) * 64;
    int hk = (bid >> 5) & 3;
    int b = bid >> 7;
    int tid = threadIdx.x;
#pragma unroll
    for (int j = 0; j < 32; j++) {
      int e = j * 256 + tid;
      int tt = e >> 7, d = e & 127;
      tile[tt][d] = qkv[(size_t)(b * TT + t0 + tt) * NQKV + NQ + NK + hk * HD + d];
    }
    __syncthreads();
#pragma unroll
    for (int j = 0; j < 32; j++) {
      int e = j * 256 + tid;
      int d = e >> 6, tt = e & 63;
      vt[(((size_t)(b * NKV + hk)) * HD + d) * TT + t0 + tt] = tile[tt][d];
    }
  }
}

// ---------- flash attention v4 (causal, GQA) ----------
// 128-q tile per block (4 waves x 32 q): every K/V frag read feeds 2 MFMAs,
// halving LDS-read traffic per unit work (the R3 bottleneck). P^T -> B-operand
// via wave-private LDS scratch (no bpermutes, no barrier). Static-max softmax.
// Longest-first 1-D grid for backfill balance; K/V dbuf prefetch.
__global__ __launch_bounds__(256, 2) void k_attn(
    const __hip_bfloat16* __restrict__ q_l, const __hip_bfloat16* __restrict__ k_l,
    const __hip_bfloat16* __restrict__ vt_l, __hip_bfloat16* __restrict__ y) {
  __shared__ __align__(16) __hip_bfloat16 Ks[2][64 * 128];   // 32 KB
  __shared__ __align__(16) __hip_bfloat16 Vs[2][128 * 64];   // 32 KB
  __shared__ __align__(16) __hip_bfloat16 Ps[4][32 * 64];    // 16 KB, per-wave scratch
  const int tid = threadIdx.x, lane = tid & 63, w = tid >> 6;
  const int q15 = lane & 15, quad = lane >> 4;
  const int id = blockIdx.x;
  const int qt = (TT / 128 - 1) - (id >> 5);  // descending: longest blocks first
  const int h = id & 15, b = (id >> 4) & 1;
  const int hk = h >> 2;
  const int nkb = 2 * qt + 2;

  const __hip_bfloat16* kbase = k_l + (size_t)(b * NKV + hk) * TT * HD;
  const __hip_bfloat16* vbase = vt_l + (size_t)(b * NKV + hk) * HD * TT;
  const __hip_bfloat16* qbase = q_l + ((size_t)(b * NH + h) * TT + qt * 128) * HD;

  auto stage = [&](int kb, int buf) {
#pragma unroll
    for (int i = 0; i < 4; i++) {
      int s = i * 256 + tid;
      int rk = s >> 4, ck = s & 15;
      gl_lds16(kbase + (size_t)(kb * 64 + rk) * HD + (ck ^ (rk & 15)) * 8,
               Ks[buf] + (i * 256 + (tid & ~63)) * 8);
      int rv = s >> 3, cv = s & 7;
      gl_lds16(vbase + (size_t)rv * TT + kb * 64 + (cv ^ (rv & 7)) * 8,
               Vs[buf] + (i * 256 + (tid & ~63)) * 8);
    }
  };

  // Q frags: wave covers q rows qt*128 + w*32 + qh*16 + q15
  bf16x8 qf[4][2];
#pragma unroll
  for (int dc = 0; dc < 4; dc++)
#pragma unroll
    for (int qh = 0; qh < 2; qh++)
      qf[dc][qh] = *(const bf16x8*)(qbase + (size_t)(w * 32 + qh * 16 + q15) * HD +
                                    dc * 32 + quad * 8);

  __hip_bfloat16* pw = Ps[w];  // this wave's P scratch: [32 q][64 k], XOR-swizzled
  const int qrow0 = q15, qrow1 = 16 + q15;
  // P write addresses (elements): row*64 + ((kt*2+(quad>>1)) ^ (row&7))*8 + (quad&1)*4
  const int pw_c = 2 * 0 + (quad >> 1);  // kt-dependent part added in loop
  const int pw_h = (quad & 1) * 4;

  floatx4 ot[8][2] = {};
  float lsum[2] = {0.0f, 0.0f};
  int cur = 0;
  const int kb_last_w = 2 * qt + (w >> 1);  // waves 0,1 skip final all-masked iter

  for (int kb = 0; kb < nkb; kb++) {
    __syncthreads();
    if (kb == 0) {
      stage(0, cur);
      __syncthreads();
    }
    if (kb + 1 < nkb) stage(kb + 1, cur ^ 1);

    if (kb <= kb_last_w) {
      // S^T = K @ Q^T : [64 k][32 q] as two 16-col C-tiles per kt
      floatx4 st[4][2] = {};
#pragma unroll
      for (int kt = 0; kt < 4; kt++) {
        int r = kt * 16 + q15;
#pragma unroll
        for (int dc = 0; dc < 4; dc++) {
          int c = dc * 4 + quad;
          bf16x8 kf = *(const bf16x8*)(Ks[cur] + (r * 16 + (c ^ (r & 15))) * 8);
          st[kt][0] = mfma16(kf, qf[dc][0], st[kt][0]);
          st[kt][1] = mfma16(kf, qf[dc][1], st[kt][1]);
        }
      }
      if (kb >= 2 * qt) {  // causal mask (diagonal region)
#pragma unroll
        for (int qh = 0; qh < 2; qh++) {
          int qg = qt * 128 + w * 32 + qh * 16 + q15;
#pragma unroll
          for (int kt = 0; kt < 4; kt++)
#pragma unroll
            for (int r = 0; r < 4; r++)
              if (kb * 64 + kt * 16 + quad * 4 + r > qg) st[kt][qh][r] = -INFINITY;
        }
      }
      // static-max softmax: p = exp2(s); write P to wave-private LDS in B layout
#pragma unroll
      for (int kt = 0; kt < 4; kt++) {
#pragma unroll
        for (int qh = 0; qh < 2; qh++) {
          float p0 = exp2f(st[kt][qh][0]);
          float p1 = exp2f(st[kt][qh][1]);
          float p2 = exp2f(st[kt][qh][2]);
          float p3 = exp2f(st[kt][qh][3]);
          lsum[qh] += (p0 + p1) + (p2 + p3);
          int2 pv;
          pv.x = pk2(p0, p1);
          pv.y = pk2(p2, p3);
          int row = qh * 16 + q15;
          int c4 = (kt * 2 + (quad >> 1)) ^ (row & 7);
          *(int2*)(pw + row * 64 + c4 * 8 + pw_h) = pv;
        }
      }
      // PV: y^T[128 d][32 q] += V^T @ P^T ; V-frag reused across both q-halves
#pragma unroll
      for (int kc = 0; kc < 2; kc++) {
        bf16x8 pf[2];
#pragma unroll
        for (int qh = 0; qh < 2; qh++) {
          int row = qh * 16 + q15;
          int c4 = (kc * 4 + quad) ^ (row & 7);
          pf[qh] = *(const bf16x8*)(pw + row * 64 + c4 * 8);
        }
#pragma unroll
        for (int dt = 0; dt < 8; dt++) {
          int r = dt * 16 + q15, c = kc * 4 + quad;
          bf16x8 vf = *(const bf16x8*)(Vs[cur] + (r * 8 + (c ^ (r & 7))) * 8);
          ot[dt][0] = mfma16(vf, pf[0], ot[dt][0]);
          ot[dt][1] = mfma16(vf, pf[1], ot[dt][1]);
        }
      }
    }
    cur ^= 1;
  }
  // epilogue: reduce l across quads, normalize, store y[b][t][h*128+d]
#pragma unroll
  for (int qh = 0; qh < 2; qh++) {
    float ls = lsum[qh];
    ls += __shfl_xor(ls, 16, 64);
    ls += __shfl_xor(ls, 32, 64);
    float linv = 1.0f / ls;
    int t = qt * 128 + w * 32 + qh * 16 + q15;
    __hip_bfloat16* yrow = y + (size_t)(b * TT + t) * TC + h * HD;
#pragma unroll
    for (int dt = 0; dt < 8; dt++) {
      int d = dt * 16 + quad * 4;
      ushort4 o;
      o.x = (unsigned short)bfbits(ot[dt][qh][0] * linv);
      o.y = (unsigned short)bfbits(ot[dt][qh][1] * linv);
      o.z = (unsigned short)bfbits(ot[dt][qh][2] * linv);
      o.w = (unsigned short)bfbits(ot[dt][qh][3] * linv);
      *(ushort4*)(yrow + d) = o;
    }
  }
}

// ---------- launcher ----------
extern "C" void kernel_launch(void* const* d_in, const int* in_sizes, int n_in,
                              void* d_out, int out_size, void* d_ws, size_t ws_size,
                              hipStream_t stream) {
  (void)in_sizes; (void)n_in; (void)out_size; (void)ws_size;
  const float* x  = (const float*)d_in[0];
  const float* Wq = (const float*)d_in[1];
  const float* Wk = (const float*)d_in[2];
  const float* Wv = (const float*)d_in[3];
  const float* Wo = (const float*)d_in[4];
  float* out = (float*)d_out;

  char* ws = (char*)d_ws;
  size_t off = 0;
  auto alloc = [&](size_t bytes) {
    void* p = ws + off;
    off += (bytes + 255) & ~(size_t)255;
    return p;
  };
  __hip_bfloat16* xb   = (__hip_bfloat16*)alloc((size_t)MR * TC * 2);
  __hip_bfloat16* wqkv = (__hip_bfloat16*)alloc((size_t)NQKV * TC * 2);
  __hip_bfloat16* wo   = (__hip_bfloat16*)alloc((size_t)TC * TC * 2);
  __hip_bfloat16* qkv  = (__hip_bfloat16*)alloc((size_t)MR * NQKV * 2);
  __hip_bfloat16* q_l  = (__hip_bfloat16*)alloc((size_t)TB * NH * TT * HD * 2);
  __hip_bfloat16* k_l  = (__hip_bfloat16*)alloc((size_t)TB * NKV * TT * HD * 2);
  __hip_bfloat16* vt_l = (__hip_bfloat16*)alloc((size_t)TB * NKV * HD * TT * 2);
  __hip_bfloat16* yb   = (__hip_bfloat16*)alloc((size_t)MR * TC * 2);

  k_cvt5<<<dim3((MR * TC / 4 + 255) / 256, 5), 256, 0, stream>>>(
      x, Wq, Wk, Wv, Wo,
      xb, wqkv, wqkv + (size_t)NQ * TC, wqkv + (size_t)(NQ + NK) * TC, wo);

  k_gemm_bt<__hip_bfloat16><<<dim3(NQKV / 128, MR / 128), 256, 0, stream>>>(
      xb, wqkv, qkv, MR, NQKV, TC);

  k_prep<<<ROPE_BLOCKS + TB * NKV * (TT / 64), 256, 0, stream>>>(qkv, q_l, k_l, vt_l);

  // flash attention: 16 q-tiles x 16 heads x 2 batch = 512 blocks, longest first
  k_attn<<<(TT / 128) * NH * TB, 256, 0, stream>>>(q_l, k_l, vt_l, yb);

  k_gemm_bt<float><<<dim3(TC / 128, MR / 128), 256, 0, stream>>>(
      yb, wo, out, MR, TC, TC);
}